// Round 1
// baseline (184.107 us; speedup 1.0000x reference)
//
#include <hip/hip_runtime.h>

// ---------------------------------------------------------------------------
// RCLayer softmax: out = softmax_rows( 1 / (1 + ||x_i - c_j||^2) )
// M=32768 rows, K=512 dims, N=2048 clusters. Output fp32 [M][N].
// Strategy: bf16 MFMA GEMM for x.c^T fused with row-softmax (block owns a full
// 32-row x 2048-col stripe). ||x||^2 / ||c||^2 computed in fp32 exactly.
// ---------------------------------------------------------------------------

typedef __attribute__((ext_vector_type(4)))  float          f32x4;
typedef __attribute__((ext_vector_type(16))) float          f32x16;
typedef __attribute__((ext_vector_type(8)))  __bf16         bf16x8;
typedef __attribute__((ext_vector_type(4)))  unsigned short u16x4;
typedef __attribute__((ext_vector_type(8)))  unsigned short u16x8;

#define AS1 __attribute__((address_space(1)))
#define AS3 __attribute__((address_space(3)))

__device__ __forceinline__ void gl2lds16(const void* g, void* l) {
  // async global->LDS, 16B per lane; LDS dest = uniform base + lane*16
  __builtin_amdgcn_global_load_lds((const AS1 unsigned int*)g,
                                   (AS3 unsigned int*)l, 16, 0, 0);
}

__device__ __forceinline__ unsigned short f2bf(float f) {  // RNE f32->bf16
  unsigned int u = __float_as_uint(f);
  u += 0x7FFFu + ((u >> 16) & 1u);
  return (unsigned short)(u >> 16);
}

__device__ __forceinline__ float fastrcp(float x) {
  float r; asm("v_rcp_f32 %0, %1" : "=v"(r) : "v"(x)); return r;
}

// ---------------------------------------------------------------------------
// Kernel 1: clusters f32[2048][512] -> bf16 chunk-images in ws (pre-swizzled
// so GEMM stages with linear global_load_lds), + c2[n] = ||c_n||^2 in fp32.
// Chunk (kc,nc) = cols [nc*256,+256) x k [kc*64,+64), 32KB each, at
// byte offset (kc*8+nc)*32768.  Within chunk: LDS image with byte address
// (r*128 + 2c) ^ ((r&7)<<4)   (r = col-in-chunk 0..255, c = k-in-chunk 0..63)
// ---------------------------------------------------------------------------
__global__ __launch_bounds__(256) void prep_clusters(
    const float* __restrict__ C, unsigned short* __restrict__ Bws,
    float* __restrict__ c2)
{
  const int t   = blockIdx.x * 256 + threadIdx.x;  // 0..131071
  const int n   = t >> 6;                          // cluster 0..2047 (1 wave per cluster)
  const int oct = t & 63;                          // k-octet 0..63
  const float* src = C + (size_t)n * 512 + oct * 8;
  f32x4 v0 = *(const f32x4*)src;
  f32x4 v1 = *(const f32x4*)(src + 4);
  float ss = v0.x*v0.x + v0.y*v0.y + v0.z*v0.z + v0.w*v0.w
           + v1.x*v1.x + v1.y*v1.y + v1.z*v1.z + v1.w*v1.w;
  u16x8 h;
  h[0]=f2bf(v0.x); h[1]=f2bf(v0.y); h[2]=f2bf(v0.z); h[3]=f2bf(v0.w);
  h[4]=f2bf(v1.x); h[5]=f2bf(v1.y); h[6]=f2bf(v1.z); h[7]=f2bf(v1.w);
  const int kc = oct >> 3, c8 = oct & 7;
  const int nc = n >> 8,   r  = n & 255;
  char* dst = (char*)Bws + (size_t)(kc * 8 + nc) * 32768
            + (size_t)(((r << 3) + (c8 ^ (r & 7))) * 16);
  *(u16x8*)dst = h;
  // ||c||^2: full-wave reduce (64 lanes = 64 octets of one cluster)
  ss += __shfl_xor(ss, 1);  ss += __shfl_xor(ss, 2);  ss += __shfl_xor(ss, 4);
  ss += __shfl_xor(ss, 8);  ss += __shfl_xor(ss, 16); ss += __shfl_xor(ss, 32);
  if ((threadIdx.x & 63) == 0) c2[n] = ss;
}

// ---------------------------------------------------------------------------
// Kernel 2: fused GEMM + softmax.  Block = 32 rows x 2048 cols, 8 waves.
// Wave w owns cols {nc*256 + w*32 + (lane&31)} for nc=0..7 -> acc[8] f32x16.
// B streamed as 64 chunks of 32KB via global_load_lds, 3-buffer pipeline,
// counted vmcnt(4) + raw s_barrier (one barrier per chunk window).
// ---------------------------------------------------------------------------
__global__ __launch_bounds__(512, 2) void fused_kernel(
    const float* __restrict__ A, const unsigned short* __restrict__ Bws,
    const float* __restrict__ c2, float* __restrict__ out)
{
  __shared__ __align__(16) unsigned short A_sh[32 * 512];  // 32KB swizzled bf16
  __shared__ __align__(16) char B_sh[3 * 32768];           // 96KB, 3 buffers
  __shared__ float x2_lds[32];
  __shared__ float wsum[8][32];
  __shared__ float inv_lds[32];

  const int tid  = threadIdx.x;
  const int wave = tid >> 6;
  const int lane = tid & 63;
  const int l31  = lane & 31;
  const int hi   = lane >> 5;
  const int brow = blockIdx.x * 32;

  // ---- A staging: fp32 -> bf16 swizzled into LDS, + exact x2 per row ----
  {
    const int r    = tid >> 4;       // row 0..31 (16 threads/row)
    const int cseg = tid & 15;
    const f32x4* ap = (const f32x4*)(A + (size_t)(brow + r) * 512);
    const int swz  = (r & 7) << 4;
    char* abase = (char*)A_sh + r * 1024;
    float ss = 0.f;
#pragma unroll
    for (int i = 0; i < 8; ++i) {
      f32x4 v = ap[cseg + 16 * i];                 // 256B-contiguous per 16 lanes
      ss += v.x*v.x + v.y*v.y + v.z*v.z + v.w*v.w;
      u16x4 hh; hh.x=f2bf(v.x); hh.y=f2bf(v.y); hh.z=f2bf(v.z); hh.w=f2bf(v.w);
      *(u16x4*)(abase + ((cseg * 8 + i * 128) ^ swz)) = hh;
    }
    ss += __shfl_xor(ss, 1); ss += __shfl_xor(ss, 2);
    ss += __shfl_xor(ss, 4); ss += __shfl_xor(ss, 8);
    if (cseg == 0) x2_lds[r] = ss;
  }
  __syncthreads();

  // ---- per-lane constant fragment offsets ----
  const int swzl = (l31 & 7) << 4;
  int off_b[4], off_a0[4];
#pragma unroll
  for (int ks = 0; ks < 4; ++ks) {
    const int k2 = ks * 32 + hi * 16;              // byte offset of k within row
    off_b[ks]  = (wave * 32 + l31) * 128 + (k2 ^ swzl);
    off_a0[ks] = l31 * 1024 + (k2 ^ swzl);         // + kc*128 per k-chunk
  }

  f32x16 acc[8];
#pragma unroll
  for (int i = 0; i < 8; ++i)
#pragma unroll
    for (int j = 0; j < 16; ++j) acc[i][j] = 0.f;

  char* bufA = B_sh;            // chunk it   (compute)
  char* bufB = B_sh + 32768;    // chunk it+1 (in flight)
  char* bufC = B_sh + 65536;    // chunk it+2 (stage target)

#define STAGE(itv, dst) {                                                      \
    const char* g_ = (const char*)Bws + (size_t)(itv) * 32768                  \
                   + wave * 4096 + lane * 16;                                  \
    char* l_ = (dst) + wave * 4096;                                            \
    gl2lds16(g_,        l_);        gl2lds16(g_ + 1024, l_ + 1024);            \
    gl2lds16(g_ + 2048, l_ + 2048); gl2lds16(g_ + 3072, l_ + 3072); }

  STAGE(0, bufA);
  STAGE(1, bufB);

  for (int kc = 0; kc < 8; ++kc) {
    bf16x8 af[4];
#pragma unroll
    for (int ks = 0; ks < 4; ++ks)
      af[ks] = *(const bf16x8*)((char*)A_sh + off_a0[ks] + kc * 128);
#pragma unroll
    for (int nc = 0; nc < 8; ++nc) {
      const int it = kc * 8 + nc;
      asm volatile("s_waitcnt vmcnt(4)" ::: "memory");  // chunk `it` landed
      __builtin_amdgcn_s_barrier();                     // all waves' parts landed
      asm volatile("" ::: "memory");
      if (it < 62) STAGE(it + 2, bufC);                 // overlaps MFMA below
#pragma unroll
      for (int ks = 0; ks < 4; ++ks) {
        bf16x8 bf = *(const bf16x8*)(bufA + off_b[ks]);
        acc[nc] = __builtin_amdgcn_mfma_f32_32x32x16_bf16(af[ks], bf, acc[nc], 0, 0, 0);
      }
      char* tp = bufA; bufA = bufB; bufB = bufC; bufC = tp;
    }
  }

  // ---- epilogue: d2 -> q -> exp, row-softmax, write ----
  // C/D layout (m74/m101): col = lane&31, row = (r&3) + 8*(r>>2) + 4*hi
  f32x4 x2v[4];
#pragma unroll
  for (int g = 0; g < 4; ++g) x2v[g] = *(const f32x4*)&x2_lds[8 * g + 4 * hi];
  float c2v[8];
#pragma unroll
  for (int nc = 0; nc < 8; ++nc) c2v[nc] = c2[nc * 256 + wave * 32 + l31];

  float p[16];
#pragma unroll
  for (int r = 0; r < 16; ++r) p[r] = 0.f;
#pragma unroll
  for (int nc = 0; nc < 8; ++nc) {
#pragma unroll
    for (int r = 0; r < 16; ++r) {
      float d2 = x2v[r >> 2][r & 3] + c2v[nc] - 2.f * acc[nc][r];
      d2 = fmaxf(d2, 0.f);
      float q = fastrcp(1.f + d2);
      float e = __expf(q);
      acc[nc][r] = e;
      p[r] += e;
    }
  }
  // reduce across the 32 cols held by this half-wave
#pragma unroll
  for (int r = 0; r < 16; ++r) {
    p[r] += __shfl_xor(p[r], 1);  p[r] += __shfl_xor(p[r], 2);
    p[r] += __shfl_xor(p[r], 4);  p[r] += __shfl_xor(p[r], 8);
    p[r] += __shfl_xor(p[r], 16);
  }
  if (l31 == 0) {
#pragma unroll
    for (int r = 0; r < 16; ++r)
      wsum[wave][(r & 3) + 8 * (r >> 2) + 4 * hi] = p[r];
  }
  __syncthreads();
  if (tid < 32) {
    float t = 0.f;
#pragma unroll
    for (int w = 0; w < 8; ++w) t += wsum[w][tid];
    inv_lds[tid] = fastrcp(t);
  }
  __syncthreads();
  f32x4 invv[4];
#pragma unroll
  for (int g = 0; g < 4; ++g) invv[g] = *(const f32x4*)&inv_lds[8 * g + 4 * hi];

  float* outp = out + (size_t)(brow + 4 * hi) * 2048 + wave * 32 + l31;
#pragma unroll
  for (int nc = 0; nc < 8; ++nc) {
#pragma unroll
    for (int r = 0; r < 16; ++r) {
      const int roff = (r & 3) + 8 * (r >> 2);
      outp[(size_t)roff * 2048 + nc * 256] = acc[nc][r] * invv[r >> 2][r & 3];
    }
  }
#undef STAGE
}

// ---------------------------------------------------------------------------
extern "C" void kernel_launch(void* const* d_in, const int* in_sizes, int n_in,
                              void* d_out, int out_size, void* d_ws, size_t ws_size,
                              hipStream_t stream) {
  const float* inputs   = (const float*)d_in[0];   // [32768][512] f32
  const float* clusters = (const float*)d_in[1];   // [2048][512] f32
  float* out = (float*)d_out;                      // [32768][2048] f32
  unsigned short* Bws = (unsigned short*)d_ws;                 // 2MB bf16 image
  float* c2 = (float*)((char*)d_ws + (2u << 20));              // 8KB fp32
  prep_clusters<<<512, 256, 0, stream>>>(clusters, Bws, c2);
  fused_kernel<<<1024, 512, 0, stream>>>(inputs, Bws, c2, out);
}

// Round 2
// 157.494 us; speedup vs baseline: 1.1690x; 1.1690x over previous
//
#include <hip/hip_runtime.h>

// ---------------------------------------------------------------------------
// RCLayer softmax: out = softmax_rows( exp(1/(1+||x_i-c_j||^2)) ) (ALPHA=1)
// M=32768, K=512, N=2048, fp32 out [M][N].
// fp8(e4m3) MFMA GEMM for x.c^T fused with row-softmax; ||x||^2/||c||^2 fp32.
// B image: 1MB fp8, k-octet-major chunks so global_load_lds stays linear and
// all LDS frag reads are lane-consecutive (bank-conflict floor).
// Output stores are non-temporal so the B image stays L2-resident.
// ---------------------------------------------------------------------------

typedef __attribute__((ext_vector_type(4)))  float        f32x4;
typedef __attribute__((ext_vector_type(16))) float        f32x16;
typedef __attribute__((ext_vector_type(2)))  unsigned int u32x2;

#define AS1 __attribute__((address_space(1)))
#define AS3 __attribute__((address_space(3)))

__device__ __forceinline__ void gl2lds16(const void* g, void* l) {
  // async global->LDS, 16B/lane; LDS dest = uniform base + lane*16
  __builtin_amdgcn_global_load_lds((const AS1 unsigned int*)g,
                                   (AS3 unsigned int*)l, 16, 0, 0);
}
__device__ __forceinline__ float fastrcp(float x) {
  float r; asm("v_rcp_f32 %0, %1" : "=v"(r) : "v"(x)); return r;
}
__device__ __forceinline__ unsigned int pk4_fp8(f32x4 v) {
  unsigned int u = 0;
  u = __builtin_amdgcn_cvt_pk_fp8_f32(v.x, v.y, u, false);
  u = __builtin_amdgcn_cvt_pk_fp8_f32(v.z, v.w, u, true);
  return u;
}

// ---------------------------------------------------------------------------
// Kernel 1: clusters f32[2048][512] -> fp8 chunk image (1MB) + fp32 c2.
// Chunk (kc 0..7, nc 0..7) = cols [nc*256,+256) x k [kc*64,+64) = 16KB at
// offset (kc*8+nc)*16384. Within chunk: [ko 0..7][c 0..255] 8B octets:
// off = ko*2048 + c*8.
// ---------------------------------------------------------------------------
__global__ __launch_bounds__(256) void prep_clusters(
    const float* __restrict__ C, unsigned char* __restrict__ Bws,
    float* __restrict__ c2)
{
  const int t   = blockIdx.x * 256 + threadIdx.x;   // 0..131071
  const int n   = t >> 6;                            // cluster
  const int oct = t & 63;                            // k-octet
  const float* src = C + (size_t)n * 512 + oct * 8;
  f32x4 v0 = *(const f32x4*)src;
  f32x4 v1 = *(const f32x4*)(src + 4);
  float ss = v0.x*v0.x + v0.y*v0.y + v0.z*v0.z + v0.w*v0.w
           + v1.x*v1.x + v1.y*v1.y + v1.z*v1.z + v1.w*v1.w;
  u32x2 h; h.x = pk4_fp8(v0); h.y = pk4_fp8(v1);
  *(u32x2*)(Bws + ((size_t)((oct >> 3) * 8 + (n >> 8)) << 14)
                + ((oct & 7) << 11) + ((size_t)(n & 255) << 3)) = h;
  ss += __shfl_xor(ss, 1);  ss += __shfl_xor(ss, 2);  ss += __shfl_xor(ss, 4);
  ss += __shfl_xor(ss, 8);  ss += __shfl_xor(ss, 16); ss += __shfl_xor(ss, 32);
  if ((threadIdx.x & 63) == 0) c2[n] = ss;
}

// ---------------------------------------------------------------------------
// Kernel 2: fused GEMM + softmax. Block = 32 rows x 2048 cols, 8 waves.
// Window = chunk-PAIR (512 cols x 64k, 32KB): 8 MFMAs/wave, 2 indep chains.
// 3-buffer pipeline, vmcnt(4) counted (vmcnt(0) drain on final window).
// A_sh: [g 0..63][r 0..31] 8B octets, 264B padded stride (uniform banks).
// ---------------------------------------------------------------------------
__global__ __launch_bounds__(512, 2) void fused_kernel(
    const float* __restrict__ A, const unsigned char* __restrict__ Bws,
    const float* __restrict__ c2, float* __restrict__ out)
{
  __shared__ __align__(16) unsigned char A_sh[64 * 264];   // 16.5KB fp8
  __shared__ __align__(16) unsigned char B_sh[3 * 32768];  // 96KB
  __shared__ float x2_lds[32];
  __shared__ float wsum[8][32];
  __shared__ float inv_lds[32];

  const int tid  = threadIdx.x;
  const int wave = tid >> 6;
  const int lane = tid & 63;
  const int l31  = lane & 31;
  const int hi   = lane >> 5;
  const int brow = blockIdx.x * 32;

  // ---- A staging: fp32 -> fp8 octet layout in LDS, exact fp32 x2 ----
  {
    const int r   = tid >> 4;        // row 0..31
    const int seg = tid & 15;        // 32-float segment
    const f32x4* ap = (const f32x4*)(A + (size_t)(brow + r) * 512 + seg * 32);
    float ss = 0.f;
#pragma unroll
    for (int i2 = 0; i2 < 4; ++i2) {
      f32x4 va = ap[2 * i2];
      f32x4 vb = ap[2 * i2 + 1];
      ss += va.x*va.x + va.y*va.y + va.z*va.z + va.w*va.w
          + vb.x*vb.x + vb.y*vb.y + vb.z*vb.z + vb.w*vb.w;
      u32x2 h; h.x = pk4_fp8(va); h.y = pk4_fp8(vb);
      *(u32x2*)(A_sh + (seg * 4 + i2) * 264 + r * 8) = h;
    }
    ss += __shfl_xor(ss, 1); ss += __shfl_xor(ss, 2);
    ss += __shfl_xor(ss, 4); ss += __shfl_xor(ss, 8);
    if (seg == 0) x2_lds[r] = ss;
  }
  __syncthreads();

  // ---- per-lane fragment offsets (all lane-consecutive reads) ----
  int off_b[4][2], off_a[4];
#pragma unroll
  for (int ks = 0; ks < 4; ++ks) {
    off_a[ks] = (ks * 2 + hi) * 264 + l31 * 8;
#pragma unroll
    for (int ncl = 0; ncl < 2; ++ncl)
      off_b[ks][ncl] = ncl * 16384 + (ks * 2 + hi) * 2048 + (wave * 32 + l31) * 8;
  }

  f32x16 acc[8];
#pragma unroll
  for (int i = 0; i < 8; ++i)
#pragma unroll
    for (int j = 0; j < 16; ++j) acc[i][j] = 0.f;

  unsigned char* bufA = B_sh;
  unsigned char* bufB = B_sh + 32768;
  unsigned char* bufC = B_sh + 65536;

#define STAGE(itv, dst) {                                                      \
    const unsigned char* g_ = Bws + (size_t)(itv) * 32768                      \
                            + wave * 4096 + lane * 16;                         \
    unsigned char* l_ = (dst) + wave * 4096;                                   \
    gl2lds16(g_,        l_);        gl2lds16(g_ + 1024, l_ + 1024);            \
    gl2lds16(g_ + 2048, l_ + 2048); gl2lds16(g_ + 3072, l_ + 3072); }

  STAGE(0, bufA);
  STAGE(1, bufB);

  for (int kc = 0; kc < 8; ++kc) {
    long af[4];
#pragma unroll
    for (int ks = 0; ks < 4; ++ks)
      af[ks] = *(const long*)(A_sh + kc * (8 * 264) + off_a[ks]);
#pragma unroll
    for (int ncp = 0; ncp < 4; ++ncp) {
      const int it = kc * 4 + ncp;
      if (kc == 7 && ncp == 3) {
        asm volatile("s_waitcnt vmcnt(0)" ::: "memory");   // final drain
      } else {
        asm volatile("s_waitcnt vmcnt(4)" ::: "memory");   // pair `it` landed
      }
      __builtin_amdgcn_sched_barrier(0);
      __builtin_amdgcn_s_barrier();
      asm volatile("" ::: "memory");
      if (it < 30) STAGE(it + 2, bufC);                    // overlaps MFMAs
      const int nc0 = ncp * 2;
#pragma unroll
      for (int ks = 0; ks < 4; ++ks) {
        long b0 = *(const long*)(bufA + off_b[ks][0]);
        long b1 = *(const long*)(bufA + off_b[ks][1]);
        acc[nc0]     = __builtin_amdgcn_mfma_f32_32x32x16_fp8_fp8(af[ks], b0, acc[nc0],     0, 0, 0);
        acc[nc0 + 1] = __builtin_amdgcn_mfma_f32_32x32x16_fp8_fp8(af[ks], b1, acc[nc0 + 1], 0, 0, 0);
      }
      unsigned char* tp = bufA; bufA = bufB; bufB = bufC; bufC = tp;
    }
  }

  // ---- epilogue: d2 -> q -> exp, row-softmax, nt-write ----
  // C/D layout: col = lane&31, row = (r&3) + 8*(r>>2) + 4*hi
  f32x4 x2v[4];
#pragma unroll
  for (int g = 0; g < 4; ++g) x2v[g] = *(const f32x4*)&x2_lds[8 * g + 4 * hi];
  float c2v[8];
#pragma unroll
  for (int nc = 0; nc < 8; ++nc) c2v[nc] = c2[nc * 256 + wave * 32 + l31];

  float p[16];
#pragma unroll
  for (int r = 0; r < 16; ++r) p[r] = 0.f;
#pragma unroll
  for (int nc = 0; nc < 8; ++nc) {
#pragma unroll
    for (int r = 0; r < 16; ++r) {
      float d2 = x2v[r >> 2][r & 3] + c2v[nc] - 2.f * acc[nc][r];
      d2 = fmaxf(d2, 0.f);
      float q = fastrcp(1.f + d2);
      float e = __expf(q);
      acc[nc][r] = e;
      p[r] += e;
    }
  }
#pragma unroll
  for (int r = 0; r < 16; ++r) {
    p[r] += __shfl_xor(p[r], 1);  p[r] += __shfl_xor(p[r], 2);
    p[r] += __shfl_xor(p[r], 4);  p[r] += __shfl_xor(p[r], 8);
    p[r] += __shfl_xor(p[r], 16);
  }
  if (l31 == 0) {
#pragma unroll
    for (int r = 0; r < 16; ++r)
      wsum[wave][(r & 3) + 8 * (r >> 2) + 4 * hi] = p[r];
  }
  __syncthreads();
  if (tid < 32) {
    float t = 0.f;
#pragma unroll
    for (int w = 0; w < 8; ++w) t += wsum[w][tid];
    inv_lds[tid] = fastrcp(t);
  }
  __syncthreads();
  f32x4 invv[4];
#pragma unroll
  for (int g = 0; g < 4; ++g) invv[g] = *(const f32x4*)&inv_lds[8 * g + 4 * hi];

  float* outp = out + (size_t)(brow + 4 * hi) * 2048 + wave * 32 + l31;
#pragma unroll
  for (int nc = 0; nc < 8; ++nc) {
#pragma unroll
    for (int r = 0; r < 16; ++r) {
      const int roff = (r & 3) + 8 * (r >> 2);
      __builtin_nontemporal_store(acc[nc][r] * invv[r >> 2][r & 3],
                                  outp + (size_t)roff * 2048 + nc * 256);
    }
  }
#undef STAGE
}

// ---------------------------------------------------------------------------
extern "C" void kernel_launch(void* const* d_in, const int* in_sizes, int n_in,
                              void* d_out, int out_size, void* d_ws, size_t ws_size,
                              hipStream_t stream) {
  const float* inputs   = (const float*)d_in[0];   // [32768][512] f32
  const float* clusters = (const float*)d_in[1];   // [2048][512] f32
  float* out = (float*)d_out;                      // [32768][2048] f32
  unsigned char* Bws = (unsigned char*)d_ws;               // 1MB fp8 image
  float* c2 = (float*)((char*)d_ws + (1u << 20));          // 8KB fp32
  prep_clusters<<<512, 256, 0, stream>>>(clusters, Bws, c2);
  fused_kernel<<<1024, 512, 0, stream>>>(inputs, Bws, c2, out);
}